// Round 6
// baseline (1081.600 us; speedup 1.0000x reference)
//
#include <hip/hip_runtime.h>

#define B_  64
#define T_  512
#define D_  64
#define U_  256
#define G4  1024   // 4*U
#define NT  512    // 8 waves, 2 per SIMD (forced by static LDS > 80 KB)

// U storage split: 13 columns per 16-col group in registers (208 VGPRs),
// 3 columns in LDS. LDS-U geometry (measured conflict-free in round 3):
// region index R = g + 64*jj (jj-major => odd g-multiplier), stride 132 u32.
#define NREGC 13
#define LDSU_STRIDE 132                       // u32; 528 B, 16B-aligned

typedef _Float16 f16x2 __attribute__((ext_vector_type(2)));
typedef unsigned int ux16 __attribute__((ext_vector_type(16)));
union U32H2 { unsigned int u; f16x2 h; unsigned short s[2]; };

__device__ __forceinline__ float dot2(unsigned int a, unsigned int b, float c) {
    U32H2 ua, ub; ua.u = a; ub.u = b;
#if __has_builtin(__builtin_amdgcn_fdot2)
    return __builtin_amdgcn_fdot2(ua.h, ub.h, c, false);
#else
    return c + (float)ua.h.x * (float)ub.h.x + (float)ua.h.y * (float)ub.h.y;
#endif
}

template <int CTRL>
__device__ __forceinline__ float dpp_mov_f32(float x) {
    int m = __builtin_amdgcn_update_dpp(0, __float_as_int(x), CTRL, 0xF, 0xF, true);
    return __int_as_float(m);
}

__device__ __forceinline__ float sigmoidf_(float z) {
    return 1.f / (1.f + __expf(-z));
}

// ---------------------------------------------------------------------------
// Kernel 1: xz[t*B+b][g] = bias[g] + sum_d x[b][t][d] * W[d][g]   (fp32 exact)
// ---------------------------------------------------------------------------
__global__ __launch_bounds__(256) void xz_kernel(const float* __restrict__ x,
                                                 const float* __restrict__ W,
                                                 const float* __restrict__ bias,
                                                 float* __restrict__ xz) {
    __shared__ float xt[16][D_];
    const int g    = blockIdx.x * 256 + threadIdx.x;
    const int row0 = blockIdx.y * 16;

    #pragma unroll
    for (int j = 0; j < 4; ++j) {
        int e = threadIdx.x + 256 * j;
        int r = e >> 6, d = e & 63;
        int row = row0 + r;
        int t = row >> 6, b = row & 63;         // row = t*64 + b
        xt[r][d] = x[((size_t)b * T_ + t) * D_ + d];
    }
    __syncthreads();

    float acc[16];
    #pragma unroll
    for (int r = 0; r < 16; ++r) acc[r] = 0.f;

    for (int d = 0; d < D_; ++d) {
        float w = W[(size_t)d * G4 + g];
        #pragma unroll
        for (int r = 0; r < 16; ++r) acc[r] += xt[r][d] * w;
    }

    float bg = bias[g];
    #pragma unroll
    for (int r = 0; r < 16; ++r)
        xz[(size_t)(row0 + r) * G4 + g] = acc[r] + bg;
}

// ---------------------------------------------------------------------------
// Kernel 2: sequential scan, one WG (512 thr) per batch element.
// thread tau = (g = tau>>3, r = tau&7). Group g owns cols 16g..16g+15; slice r
// owns pairs [16r,16r+16) (k = 32r..32r+31). U f16: cols 0..12 in 13 named
// ux16 SSA vectors; cols 13..15 in STATIC LDS (so the compiler knows only one
// WG fits per CU -> 2 waves/SIMD -> 256-VGPR budget).
// ---------------------------------------------------------------------------

struct LstmSmem {
    unsigned int  lds_u[192 * LDSU_STRIDE];   // 101376 B
    unsigned short h16[8 * 40];               // 8 slices x 80 B = 640 B
    float          z[G4];                     // 4096 B
    float          pd[U_];                    // 1024 B
};                                            // total 107136 B (< 163840)

// pack U[2*(16r+p)][col], U[2*(16r+p)+1][col] -> u32 of 2 f16
#define PACKP(p_) __extension__ ({                                            \
    U32H2 a_;                                                                 \
    a_.h = f16x2{(_Float16)Um[(size_t)(2 * (16 * r + (p_))) * G4 + col],      \
                 (_Float16)Um[(size_t)(2 * (16 * r + (p_)) + 1) * G4 + col]}; \
    a_.u; })

#define INIT_UCOL(UV, jj) {                                   \
    const int col = 16 * g + (jj);                            \
    UV.s0 = PACKP(0);  UV.s1 = PACKP(1);  UV.s2 = PACKP(2);   \
    UV.s3 = PACKP(3);  UV.s4 = PACKP(4);  UV.s5 = PACKP(5);   \
    UV.s6 = PACKP(6);  UV.s7 = PACKP(7);  UV.s8 = PACKP(8);   \
    UV.s9 = PACKP(9);  UV.sa = PACKP(10); UV.sb = PACKP(11);  \
    UV.sc = PACKP(12); UV.sd = PACKP(13); UV.se = PACKP(14);  \
    UV.sf = PACKP(15);                                        \
    __builtin_amdgcn_sched_barrier(0); }

#define DOTC(UV, ACC, S0, S1, S2, S3) {      \
    ACC = dot2(UV.S0, hp0, ACC);             \
    ACC = dot2(UV.S1, hp1, ACC);             \
    ACC = dot2(UV.S2, hp2, ACC);             \
    ACC = dot2(UV.S3, hp3, ACC); }

#define DOTQ(Q, ACC) {                       \
    ACC = dot2(Q.x, hp0, ACC);               \
    ACC = dot2(Q.y, hp1, ACC);               \
    ACC = dot2(Q.z, hp2, ACC);               \
    ACC = dot2(Q.w, hp3, ACC); }

#define DOT_CHUNK(I, S0, S1, S2, S3) {                                  \
    const uint4 h4 = hq[I];                                             \
    const unsigned int hp0 = h4.x, hp1 = h4.y, hp2 = h4.z, hp3 = h4.w;  \
    DOTC(u0,  acc0,  S0, S1, S2, S3)                                    \
    DOTC(u1,  acc1,  S0, S1, S2, S3)                                    \
    DOTC(u2,  acc2,  S0, S1, S2, S3)                                    \
    DOTC(u3,  acc3,  S0, S1, S2, S3)                                    \
    DOTC(u4,  acc4,  S0, S1, S2, S3)                                    \
    DOTC(u5,  acc5,  S0, S1, S2, S3)                                    \
    DOTC(u6,  acc6,  S0, S1, S2, S3)                                    \
    DOTC(u7,  acc7,  S0, S1, S2, S3)                                    \
    DOTC(u8,  acc8,  S0, S1, S2, S3)                                    \
    DOTC(u9,  acc9,  S0, S1, S2, S3)                                    \
    DOTC(u10, acc10, S0, S1, S2, S3)                                    \
    DOTC(u11, acc11, S0, S1, S2, S3)                                    \
    DOTC(u12, acc12, S0, S1, S2, S3)                                    \
    { const uint4 q = lu0[I]; DOTQ(q, acc13) }                          \
    { const uint4 q = lu1[I]; DOTQ(q, acc14) }                          \
    { const uint4 q = lu2[I]; DOTQ(q, acc15) } }

#define RED(ACC) {                          \
    ACC += dpp_mov_f32<0xB1>(ACC);          \
    ACC += dpp_mov_f32<0x4E>(ACC);          \
    ACC += dpp_mov_f32<0x141>(ACC); }

#if __has_attribute(amdgpu_num_vgpr)
#define LSTM_VGPR_ATTR __attribute__((amdgpu_num_vgpr(256)))
#else
#define LSTM_VGPR_ATTR
#endif

__global__
__attribute__((amdgpu_flat_work_group_size(NT, NT), amdgpu_waves_per_eu(2, 2)))
LSTM_VGPR_ATTR
void lstm_kernel(
        const float* __restrict__ Um,
        const float* __restrict__ dw,
        const float* __restrict__ dbp,
        const float* __restrict__ xz,
        float* __restrict__ out) {
    __shared__ LstmSmem sm;

    const int tau = threadIdx.x;
    const int b   = blockIdx.x;
    const int g   = tau >> 3;
    const int r   = tau & 7;

    // ---- one-time: register-resident U (cols j=0..12 of group g) ----
    ux16 u0, u1, u2, u3, u4, u5, u6, u7, u8, u9, u10, u11, u12;
    INIT_UCOL(u0, 0)   INIT_UCOL(u1, 1)   INIT_UCOL(u2, 2)
    INIT_UCOL(u3, 3)   INIT_UCOL(u4, 4)   INIT_UCOL(u5, 5)
    INIT_UCOL(u6, 6)   INIT_UCOL(u7, 7)   INIT_UCOL(u8, 8)
    INIT_UCOL(u9, 9)   INIT_UCOL(u10, 10) INIT_UCOL(u11, 11)
    INIT_UCOL(u12, 12)

    // ---- one-time: LDS-resident U cols 13..15. Region R = g + 64*jj ----
    for (int idx = tau; idx < 192 * 128; idx += NT) {
        const int R = idx >> 7, p = idx & 127;
        const int gg = R & 63, jj = R >> 6;
        const int col = 16 * gg + NREGC + jj;
        U32H2 a;
        a.h = f16x2{(_Float16)Um[(size_t)(2 * p) * G4 + col],
                    (_Float16)Um[(size_t)(2 * p + 1) * G4 + col]};
        sm.lds_u[R * LDSU_STRIDE + p] = a.u;
    }
    // ---- init h = 0 ----
    if (tau < U_) sm.h16[(tau >> 5) * 40 + (tau & 31)] = 0;

    const float dwr = (tau < U_) ? dw[tau] : 0.f;
    const float db0 = dbp[0];
    float c_state = 0.f;

    // per-thread LDS read bases
    const uint4* lu0 = (const uint4*)&sm.lds_u[(g +   0) * LDSU_STRIDE + 16 * r];
    const uint4* lu1 = (const uint4*)&sm.lds_u[(g +  64) * LDSU_STRIDE + 16 * r];
    const uint4* lu2 = (const uint4*)&sm.lds_u[(g + 128) * LDSU_STRIDE + 16 * r];
    const uint4* hq  = (const uint4*)((const char*)sm.h16 + r * 80);
    const int c2 = 16 * g + 2 * r;              // the two z columns this thread owns

    float2 xzc = *(const float2*)(xz + (size_t)b * G4 + c2);   // t=0
    __syncthreads();

    for (int t = 0; t < T_; ++t) {
        // prefetch next step's xz (hides L2/L3 latency under the dot phase)
        const int tn = (t + 1 < T_) ? t + 1 : t;
        const float2 xzn = *(const float2*)(xz + ((size_t)tn * B_ + b) * G4 + c2);

        // ---- partial dots over this slice's 32 k values, 16 columns ----
        float acc0 = 0.f, acc1 = 0.f, acc2 = 0.f, acc3 = 0.f;
        float acc4 = 0.f, acc5 = 0.f, acc6 = 0.f, acc7 = 0.f;
        float acc8 = 0.f, acc9 = 0.f, acc10 = 0.f, acc11 = 0.f;
        float acc12 = 0.f, acc13 = 0.f, acc14 = 0.f, acc15 = 0.f;

        DOT_CHUNK(0, s0, s1, s2, s3)
        DOT_CHUNK(1, s4, s5, s6, s7)
        DOT_CHUNK(2, s8, s9, sa, sb)
        DOT_CHUNK(3, sc, sd, se, sf)

        // ---- 8-lane butterfly reduce on the VALU/DPP pipe ----
        RED(acc0)  RED(acc1)  RED(acc2)  RED(acc3)
        RED(acc4)  RED(acc5)  RED(acc6)  RED(acc7)
        RED(acc8)  RED(acc9)  RED(acc10) RED(acc11)
        RED(acc12) RED(acc13) RED(acc14) RED(acc15)

        // lane r keeps columns 2r, 2r+1
        float z0 = acc0, z1 = acc1;
        if (r == 1) { z0 = acc2;  z1 = acc3;  }
        if (r == 2) { z0 = acc4;  z1 = acc5;  }
        if (r == 3) { z0 = acc6;  z1 = acc7;  }
        if (r == 4) { z0 = acc8;  z1 = acc9;  }
        if (r == 5) { z0 = acc10; z1 = acc11; }
        if (r == 6) { z0 = acc12; z1 = acc13; }
        if (r == 7) { z0 = acc14; z1 = acc15; }
        z0 += xzc.x;
        z1 += xzc.y;
        *(float2*)(sm.z + c2) = float2{z0, z1};
        __syncthreads();                        // z ready

        // ---- gates + state update (threads tau < 256, u = tau) ----
        if (tau < U_) {
            const int u = tau;
            float zi = sm.z[u];
            float zf = sm.z[U_ + u];
            float zg = sm.z[2 * U_ + u];
            float zo = sm.z[3 * U_ + u];
            float ig = sigmoidf_(zi);
            float fg = sigmoidf_(zf);
            float gg = fmaxf(zg, 0.f);
            float og = sigmoidf_(zo);
            c_state = fg * c_state + ig * gg;
            float h = og * fmaxf(c_state, 0.f);
            U32H2 hb; hb.h = f16x2{(_Float16)h, (_Float16)h};
            sm.h16[(u >> 5) * 40 + (u & 31)] = hb.s[0];
            sm.pd[u] = h * dwr;
        }
        __syncthreads();                        // h (and pd) ready

        // ---- dense: sigma[b][t] = sum_u h[u]*dw[u] + db ----
        if (tau < 64) {
            float s = sm.pd[tau] + sm.pd[tau + 64] + sm.pd[tau + 128] + sm.pd[tau + 192];
            #pragma unroll
            for (int off = 32; off > 0; off >>= 1)
                s += __shfl_down(s, off);
            if (tau == 0) out[(size_t)b * T_ + t] = s + db0;
        }

        xzc = xzn;
    }
}

// ---------------------------------------------------------------------------
// Fallback (no workspace): streaming kernel, correctness only.
// ---------------------------------------------------------------------------
__global__ __launch_bounds__(1024) void lstm_fallback(
        const float* __restrict__ x,  const float* __restrict__ W,
        const float* __restrict__ Um, const float* __restrict__ bias,
        const float* __restrict__ dw, const float* __restrict__ dbp,
        float* __restrict__ out) {
    __shared__ float h_s[U_];
    __shared__ float z_s2[G4];
    __shared__ float pd_s2[U_];
    const int g = threadIdx.x;
    const int b = blockIdx.x;
    const float bg  = bias[g];
    const float dwr = (g < U_) ? dw[g] : 0.f;
    const float db0 = dbp[0];
    float c = 0.f;
    if (g < U_) h_s[g] = 0.f;
    __syncthreads();
    const float* Ucol = Um + g;
    for (int t = 0; t < T_; ++t) {
        float acc = bg;
        const float* xrow = x + ((size_t)b * T_ + t) * D_;
        for (int d = 0; d < D_; ++d) acc += xrow[d] * W[(size_t)d * G4 + g];
        for (int k = 0; k < U_; ++k) acc += h_s[k] * Ucol[(size_t)k * G4];
        z_s2[g] = acc;
        __syncthreads();
        if (g < U_) {
            float ig = sigmoidf_(z_s2[g]);
            float fg = sigmoidf_(z_s2[U_ + g]);
            float gg = fmaxf(z_s2[2 * U_ + g], 0.f);
            float og = sigmoidf_(z_s2[3 * U_ + g]);
            c = fg * c + ig * gg;
            float h = og * fmaxf(c, 0.f);
            h_s[g] = h; pd_s2[g] = h * dwr;
        }
        __syncthreads();
        if (g < 64) {
            float s = pd_s2[g] + pd_s2[g + 64] + pd_s2[g + 128] + pd_s2[g + 192];
            #pragma unroll
            for (int off = 32; off > 0; off >>= 1) s += __shfl_down(s, off);
            if (g == 0) out[(size_t)b * T_ + t] = s + db0;
        }
        __syncthreads();
    }
}

// ---------------------------------------------------------------------------
extern "C" void kernel_launch(void* const* d_in, const int* in_sizes, int n_in,
                              void* d_out, int out_size, void* d_ws, size_t ws_size,
                              hipStream_t stream) {
    const float* x    = (const float*)d_in[0];
    const float* W    = (const float*)d_in[1];
    const float* Um   = (const float*)d_in[2];
    const float* bias = (const float*)d_in[3];
    const float* dw   = (const float*)d_in[4];
    const float* db   = (const float*)d_in[5];
    float* out = (float*)d_out;

    const size_t need = (size_t)T_ * B_ * G4 * sizeof(float);   // 128 MiB
    if (ws_size >= need) {
        float* xz = (float*)d_ws;
        dim3 gridX(G4 / 256, (T_ * B_) / 16);
        xz_kernel<<<gridX, 256, 0, stream>>>(x, W, bias, xz);
        lstm_kernel<<<B_, NT, 0, stream>>>(Um, dw, db, xz, out);
    } else {
        lstm_fallback<<<B_, 1024, 0, stream>>>(x, W, Um, bias, dw, db, out);
    }
}